// Round 6
// baseline (250.515 us; speedup 1.0000x reference)
//
#include <hip/hip_runtime.h>

typedef float  f4  __attribute__((ext_vector_type(4)));
typedef __bf16 bf8 __attribute__((ext_vector_type(8)));

constexpr int B_ = 2, N_ = 1024, M_ = 256, D_ = 576, H1_ = 512, H2_ = 256;

__device__ __forceinline__ void gload_lds16(const void* g, void* l) {
    __builtin_amdgcn_global_load_lds((const __attribute__((address_space(1))) void*)g,
                                     (__attribute__((address_space(3))) void*)l, 16, 0, 0);
}

// ---------------- k_prep: 64x64 f32->bf16 transposes (W1a,W1b,W2) ----------
__global__ __launch_bounds__(256) void k_prep(
    const float* __restrict__ W1a, const float* __restrict__ W1b, const float* __restrict__ W2,
    __bf16* __restrict__ w1aT, __bf16* __restrict__ w1bT, __bf16* __restrict__ w2T) {
    __shared__ float tl[64][65];
    int bid = blockIdx.x;
    const float* src; __bf16* dst; int R, C, t0;
    if (bid < 72)       { src = W1a; dst = w1aT; R = D_;  C = H1_; t0 = bid; }
    else if (bid < 144) { src = W1b; dst = w1bT; R = D_;  C = H1_; t0 = bid - 72; }
    else                { src = W2;  dst = w2T;  R = H1_; C = H2_; t0 = bid - 144; }
    const int tilesC = C / 64;
    const int r0 = (t0 / tilesC) * 64, c0 = (t0 % tilesC) * 64;
    const int tx = threadIdx.x & 63, ty = threadIdx.x >> 6;
    #pragma unroll
    for (int i = 0; i < 16; ++i)
        tl[ty + i * 4][tx] = src[(size_t)(r0 + ty + i * 4) * C + c0 + tx];
    __syncthreads();
    #pragma unroll
    for (int i = 0; i < 16; ++i)
        dst[(size_t)(c0 + ty + i * 4) * R + r0 + tx] = (__bf16)tl[tx][ty + i * 4];
}

// ------- k_proj: Phi(f32) @ W1T -> aproj(f32,+b1) / bproj(bf16) -------------
// 128r x 128c tile, 8 waves (2x4), BK=64, double-buffered.
__global__ __launch_bounds__(512, 2) void k_proj(
    const float* __restrict__ PhiA, const float* __restrict__ PhiB,
    const __bf16* __restrict__ w1aT, const __bf16* __restrict__ w1bT,
    const float* __restrict__ b1, float* __restrict__ aproj, __bf16* __restrict__ bprojh) {
    __shared__ __bf16 as_[2][128 * 64];   // 16KB each, row=128B, XOR swz
    __shared__ __bf16 ws_[2][128 * 64];
    const int t = threadIdx.x, l15 = t & 15, g = (t >> 4) & 3, wid = t >> 6;
    const int wr = wid >> 2, wc = wid & 3;        // 2 x 4
    const int by = blockIdx.x, c0 = blockIdx.y * 128;
    const bool isA = (by < 16);
    const float* srcf = isA ? PhiA : PhiB;
    const int rows0 = isA ? by * 128 : (by - 16) * 128;
    const __bf16* wt = isA ? w1aT : w1bT;

    // A reg-stage: thread -> row ra, 16-k chunk
    const int ra = t >> 2, kc = (t & 3) * 16;

#define STG_A(buf, kk) do {                                                       \
    const float* ap_ = srcf + (size_t)(rows0 + ra) * D_ + (kk) + kc;              \
    f4 v0_ = *(const f4*)ap_, v1_ = *(const f4*)(ap_ + 4),                        \
       v2_ = *(const f4*)(ap_ + 8), v3_ = *(const f4*)(ap_ + 12);                 \
    bf8 h0_, h1_;                                                                 \
    _Pragma("unroll")                                                             \
    for (int j_ = 0; j_ < 4; ++j_) {                                              \
        h0_[j_] = (__bf16)v0_[j_]; h0_[4 + j_] = (__bf16)v1_[j_];                 \
        h1_[j_] = (__bf16)v2_[j_]; h1_[4 + j_] = (__bf16)v3_[j_];                 \
    }                                                                             \
    *(bf8*)((char*)(&as_[(buf)][0]) + ra * 128 + ((kc * 2) ^ ((ra & 7) << 4)))      = h0_; \
    *(bf8*)((char*)(&as_[(buf)][0]) + ra * 128 + ((kc * 2 + 16) ^ ((ra & 7) << 4))) = h1_; \
    } while (0)

#define STG_W(buf, kk) do {                                                       \
    _Pragma("unroll")                                                             \
    for (int i_ = 0; i_ < 2; ++i_) {                                              \
        int c_ = t + i_ * 512; int col_ = c_ >> 3; int gg_ = (c_ & 7) ^ (col_ & 7);\
        gload_lds16(wt + (size_t)(c0 + col_) * D_ + (kk) + gg_ * 8,               \
                    (char*)(&ws_[(buf)][0]) + c_ * 16);                           \
    } } while (0)

    f4 acc[4][2];
    #pragma unroll
    for (int fr = 0; fr < 4; ++fr)
        #pragma unroll
        for (int cf = 0; cf < 2; ++cf) acc[fr][cf] = (f4)0.0f;

    STG_A(0, 0); STG_W(0, 0);
    asm volatile("s_waitcnt vmcnt(0) lgkmcnt(0)" ::: "memory");
    __builtin_amdgcn_s_barrier();
    STG_A(1, 64); STG_W(1, 64);

    #pragma unroll 1
    for (int kt = 0; kt < 9; ++kt) {              // K = 576 = 9*64
        const int cur = kt & 1;
        #pragma unroll
        for (int ks = 0; ks < 2; ++ks) {
            bf8 av[4], bv[2];
            #pragma unroll
            for (int fr = 0; fr < 4; ++fr) {
                int row = wr * 64 + fr * 16 + l15;
                av[fr] = *(const bf8*)((const char*)(&as_[cur][0]) +
                         row * 128 + ((ks * 64 + g * 16) ^ ((row & 7) << 4)));
            }
            #pragma unroll
            for (int cf = 0; cf < 2; ++cf) {
                int col = wc * 32 + cf * 16 + l15;
                bv[cf] = *(const bf8*)((const char*)(&ws_[cur][0]) +
                         col * 128 + ((ks * 64 + g * 16) ^ ((col & 7) << 4)));
            }
            #pragma unroll
            for (int fr = 0; fr < 4; ++fr)
                #pragma unroll
                for (int cf = 0; cf < 2; ++cf)
                    acc[fr][cf] = __builtin_amdgcn_mfma_f32_16x16x32_bf16(av[fr], bv[cf], acc[fr][cf], 0, 0, 0);
        }
        if (kt == 8) break;
        asm volatile("s_waitcnt vmcnt(0) lgkmcnt(0)" ::: "memory");
        __builtin_amdgcn_s_barrier();
        if (kt < 7) { STG_A(cur, (kt + 2) * 64); STG_W(cur, (kt + 2) * 64); }
    }

    #pragma unroll
    for (int fr = 0; fr < 4; ++fr)
        #pragma unroll
        for (int cf = 0; cf < 2; ++cf) {
            int col = c0 + wc * 32 + cf * 16 + l15;
            int row = rows0 + wr * 64 + fr * 16 + g * 4;
            if (isA) {
                float bb = b1[col];
                #pragma unroll
                for (int j = 0; j < 4; ++j)
                    aproj[(size_t)(row + j) * H1_ + col] = acc[fr][cf][j] + bb;
            } else {
                #pragma unroll
                for (int j = 0; j < 4; ++j)
                    bprojh[(size_t)(row + j) * H1_ + col] = (__bf16)acc[fr][cf][j];
            }
        }
#undef STG_A
#undef STG_W
}

// ---------------- k_main: reg-built h1, immediate-offset LDS, BK=32 --------
__global__ __launch_bounds__(512, 2) void k_main(
    const float* __restrict__ aproj, const __bf16* __restrict__ bprojh,
    const __bf16* __restrict__ w2T, const float* __restrict__ b2,
    const float* __restrict__ w3, const float* __restrict__ b3,
    float* __restrict__ outp) {
    __shared__ float  apl[16 * 512];      // 32KB, row=2048B, linear (broadcast)
    __shared__ __bf16 bpl[16 * 512];      // 16KB, row=1024B = 64 16B-slots, swz
    __shared__ __bf16 w2l[2][256 * 32];   // 2x16KB, 128 colpair-rows x 8 slots, swz
    __shared__ float  part[2][256];       // 2KB

    const int t = threadIdx.x, l15 = t & 15, g = (t >> 4) & 3, wid = t >> 6;
    const int wr = wid >> 1, wc = wid & 1;      // 4 x 2 wave grid
    const int bid = blockIdx.x;
    const int bn0 = (bid >> 4) << 4;            // 16 aproj rows (b*N+n)
    const int m0 = (bid & 15) << 4;
    const int bprow0 = ((bn0 >> 10) << 8) + m0; // batch*256 + m0

    // ---- lane-constant LDS read offsets (K-loop uses only immediates/xor) ----
    int offA[4];
    #pragma unroll
    for (int fr = 0; fr < 4; ++fr) offA[fr] = (wr * 4 + fr) * 2048 + g * 32;
    int offB[8];
    #pragma unroll
    for (int cf = 0; cf < 8; ++cf) {
        int col = wc * 128 + cf * 16 + l15;
        int cp = col >> 1, sp = (((col & 1) << 2) + g) ^ (cp & 7);
        offB[cf] = cp * 128 + sp * 16;
    }
    const int offP = l15 * 1024 + (((g ^ (l15 & 3)) | (l15 & 4)) << 4);

#define STAGE_W2M(buf, ktn) do {                                                  \
    _Pragma("unroll")                                                             \
    for (int i_ = 0; i_ < 2; ++i_) {                                              \
        int c_ = t + i_ * 512; int cp_ = c_ >> 3; int sp_ = c_ & 7;               \
        int si_ = sp_ ^ (cp_ & 7); int col_ = cp_ * 2 + (si_ >> 2);               \
        gload_lds16(w2T + (size_t)col_ * H1_ + (ktn) * 32 + (si_ & 3) * 8,        \
                    (char*)w2l + (buf) * 16384 + c_ * 16);                        \
    } } while (0)

#define STAGE_AP() do {                                                           \
    _Pragma("unroll")                                                             \
    for (int i_ = 0; i_ < 4; ++i_) {                                              \
        int c_ = t + i_ * 512;                                                    \
        gload_lds16(aproj + (size_t)(bn0 + (c_ >> 7)) * H1_ + (c_ & 127) * 4,     \
                    (char*)apl + c_ * 16);                                        \
    } } while (0)

#define STAGE_BP() do {                                                           \
    _Pragma("unroll")                                                             \
    for (int i_ = 0; i_ < 2; ++i_) {                                              \
        int c_ = t + i_ * 512; int row_ = c_ >> 6; int kc_ = (c_ & 63) ^ (row_ & 7);\
        gload_lds16(bprojh + (size_t)(bprow0 + row_) * H1_ + kc_ * 8,             \
                    (char*)bpl + c_ * 16);                                        \
    } } while (0)

    f4 acc[4][8];
    #pragma unroll
    for (int fr = 0; fr < 4; ++fr)
        #pragma unroll
        for (int cf = 0; cf < 8; ++cf) acc[fr][cf] = (f4)0.0f;

    float b2v[8], w3v[8];
    #pragma unroll
    for (int cf = 0; cf < 8; ++cf) {
        int col = wc * 128 + cf * 16 + l15;
        b2v[cf] = b2[col]; w3v[cf] = w3[col];
    }

    // prologue: ap, bp, w2(0) resident; w2(1) in flight
    STAGE_AP(); STAGE_BP(); STAGE_W2M(0, 0); STAGE_W2M(1, 1);
    asm volatile("s_waitcnt vmcnt(2)" ::: "memory");
    __builtin_amdgcn_s_barrier();

    #pragma unroll
    for (int kt = 0; kt < 16; ++kt) {             // K = 512 = 16 * 32
        const int cur = kt & 1;
        bf8 bpv = *(const bf8*)((const char*)bpl + (offP ^ (kt * 64)));
        bf8 bv[8];
        #pragma unroll
        for (int cf = 0; cf < 8; ++cf)
            bv[cf] = *(const bf8*)((const char*)w2l + offB[cf] + cur * 16384);
        f4 a0[4], a1[4];
        #pragma unroll
        for (int fr = 0; fr < 4; ++fr) {
            a0[fr] = *(const f4*)((const char*)apl + offA[fr] + kt * 128);
            a1[fr] = *(const f4*)((const char*)apl + offA[fr] + kt * 128 + 16);
        }
        float bpf[8];
        #pragma unroll
        for (int j = 0; j < 8; ++j) bpf[j] = (float)bpv[j];
        __builtin_amdgcn_s_setprio(1);
        #pragma unroll
        for (int fr = 0; fr < 4; ++fr) {
            bf8 av;
            #pragma unroll
            for (int j = 0; j < 4; ++j) {
                av[j]     = (__bf16)fmaxf(a0[fr][j] + bpf[j],     0.0f);
                av[4 + j] = (__bf16)fmaxf(a1[fr][j] + bpf[4 + j], 0.0f);
            }
            #pragma unroll
            for (int cf = 0; cf < 8; ++cf)
                acc[fr][cf] = __builtin_amdgcn_mfma_f32_16x16x32_bf16(av, bv[cf], acc[fr][cf], 0, 0, 0);
        }
        __builtin_amdgcn_s_setprio(0);
        if (kt < 15) {
            asm volatile("" ::: "memory");
            __builtin_amdgcn_s_barrier();         // all waves done reading w2l[cur]
            if (kt < 14) STAGE_W2M(cur, kt + 2);  // refill cur; flies ~1 phase
            if (kt < 14) asm volatile("s_waitcnt vmcnt(2)" ::: "memory");
            else         asm volatile("s_waitcnt vmcnt(0)" ::: "memory");
            __builtin_amdgcn_s_barrier();         // w2l[cur^1] (kt+1) now resident
        }
    }

    // epilogue: relu(acc+b2) dot w3, reduce 16 lanes + 2 wc groups
    #pragma unroll
    for (int fr = 0; fr < 4; ++fr) {
        #pragma unroll
        for (int j = 0; j < 4; ++j) {
            float s = 0.0f;
            #pragma unroll
            for (int cf = 0; cf < 8; ++cf)
                s += fmaxf(acc[fr][cf][j] + b2v[cf], 0.0f) * w3v[cf];
            s += __shfl_xor(s, 1); s += __shfl_xor(s, 2);
            s += __shfl_xor(s, 4); s += __shfl_xor(s, 8);
            if (l15 == 0) part[wc][wr * 64 + fr * 16 + g * 4 + j] = s;
        }
    }
    __syncthreads();
    if (t < 256) {
        float o = part[0][t] + part[1][t] + b3[0];
        outp[(size_t)(bn0 + (t >> 4)) * M_ + m0 + (t & 15)] = o;
    }
#undef STAGE_W2M
#undef STAGE_AP
#undef STAGE_BP
}

extern "C" void kernel_launch(void* const* d_in, const int* in_sizes, int n_in,
                              void* d_out, int out_size, void* d_ws, size_t ws_size,
                              hipStream_t stream) {
    (void)in_sizes; (void)n_in; (void)out_size; (void)ws_size;
    const float* PhiA = (const float*)d_in[0];
    const float* PhiB = (const float*)d_in[1];
    const float* W1a  = (const float*)d_in[2];
    const float* W1b  = (const float*)d_in[3];
    const float* b1   = (const float*)d_in[4];
    const float* W2   = (const float*)d_in[5];
    const float* b2   = (const float*)d_in[6];
    const float* W3   = (const float*)d_in[7];
    const float* b3   = (const float*)d_in[8];
    float* out = (float*)d_out;

    char* ws = (char*)d_ws;
    float*  aproj  = (float*)(ws);                  // 2048*512*4 = 4,194,304
    __bf16* bprojh = (__bf16*)(ws + 4194304);       //  512*512*2 =   524,288
    __bf16* w1aT   = (__bf16*)(ws + 4718592);       //   589,824
    __bf16* w1bT   = (__bf16*)(ws + 5308416);       //   589,824
    __bf16* w2T    = (__bf16*)(ws + 5898240);       //   262,144  (total ~6.2 MB)

    k_prep<<<176, 256, 0, stream>>>(W1a, W1b, W2, w1aT, w1bT, w2T);
    k_proj<<<dim3(20, 4), 512, 0, stream>>>(PhiA, PhiB, w1aT, w1bT, b1, aproj, bprojh);
    k_main<<<2048, 512, 0, stream>>>(aproj, bprojh, w2T, b2, W3, b3, out);
}

// Round 7
// 250.312 us; speedup vs baseline: 1.0008x; 1.0008x over previous
//
#include <hip/hip_runtime.h>

typedef float  f4  __attribute__((ext_vector_type(4)));
typedef __bf16 bf8 __attribute__((ext_vector_type(8)));

constexpr int B_ = 2, N_ = 1024, M_ = 256, D_ = 576, H1_ = 512, H2_ = 256;

__device__ __forceinline__ void gload_lds16(const void* g, void* l) {
    __builtin_amdgcn_global_load_lds((const __attribute__((address_space(1))) void*)g,
                                     (__attribute__((address_space(3))) void*)l, 16, 0, 0);
}

// ---------------- k_prep: 64x64 f32->bf16 transposes (W1a,W1b,W2) ----------
__global__ __launch_bounds__(256) void k_prep(
    const float* __restrict__ W1a, const float* __restrict__ W1b, const float* __restrict__ W2,
    __bf16* __restrict__ w1aT, __bf16* __restrict__ w1bT, __bf16* __restrict__ w2T) {
    __shared__ float tl[64][65];
    int bid = blockIdx.x;
    const float* src; __bf16* dst; int R, C, t0;
    if (bid < 72)       { src = W1a; dst = w1aT; R = D_;  C = H1_; t0 = bid; }
    else if (bid < 144) { src = W1b; dst = w1bT; R = D_;  C = H1_; t0 = bid - 72; }
    else                { src = W2;  dst = w2T;  R = H1_; C = H2_; t0 = bid - 144; }
    const int tilesC = C / 64;
    const int r0 = (t0 / tilesC) * 64, c0 = (t0 % tilesC) * 64;
    const int tx = threadIdx.x & 63, ty = threadIdx.x >> 6;
    #pragma unroll
    for (int i = 0; i < 16; ++i)
        tl[ty + i * 4][tx] = src[(size_t)(r0 + ty + i * 4) * C + c0 + tx];
    __syncthreads();
    #pragma unroll
    for (int i = 0; i < 16; ++i)
        dst[(size_t)(c0 + ty + i * 4) * R + r0 + tx] = (__bf16)tl[tx][ty + i * 4];
}

// ------- k_proj: Phi(f32) @ W1T -> aprojh(bf16,+b1) / bprojh(bf16) ---------
// 64r x 128c tile, 4 waves (2x2), BK=64, double-buffered.
__global__ __launch_bounds__(256, 2) void k_proj(
    const float* __restrict__ PhiA, const float* __restrict__ PhiB,
    const __bf16* __restrict__ w1aT, const __bf16* __restrict__ w1bT,
    const float* __restrict__ b1, __bf16* __restrict__ aprojh, __bf16* __restrict__ bprojh) {
    __shared__ __bf16 as_[2][64 * 64];    // 8KB each, row=128B, XOR swz
    __shared__ __bf16 ws_[2][128 * 64];   // 16KB each
    const int t = threadIdx.x, l15 = t & 15, g = (t >> 4) & 3, wid = t >> 6;
    const int wr = wid >> 1, wc = wid & 1;        // 2 x 2 waves
    const int by = blockIdx.x, c0 = blockIdx.y * 128;
    const bool isA = (by < 32);
    const float* srcf = isA ? PhiA : PhiB;
    const int rows0 = isA ? by * 64 : (by - 32) * 64;
    const __bf16* wt = isA ? w1aT : w1bT;

    const int ra = t >> 2, kc = (t & 3) * 16;     // A reg-stage: row, 16-k chunk

#define STG_A(buf, kk) do {                                                       \
    const float* ap_ = srcf + (size_t)(rows0 + ra) * D_ + (kk) + kc;              \
    f4 v0_ = *(const f4*)ap_, v1_ = *(const f4*)(ap_ + 4),                        \
       v2_ = *(const f4*)(ap_ + 8), v3_ = *(const f4*)(ap_ + 12);                 \
    bf8 h0_, h1_;                                                                 \
    _Pragma("unroll")                                                             \
    for (int j_ = 0; j_ < 4; ++j_) {                                              \
        h0_[j_] = (__bf16)v0_[j_]; h0_[4 + j_] = (__bf16)v1_[j_];                 \
        h1_[j_] = (__bf16)v2_[j_]; h1_[4 + j_] = (__bf16)v3_[j_];                 \
    }                                                                             \
    *(bf8*)((char*)(&as_[(buf)][0]) + ra * 128 + ((kc * 2) ^ ((ra & 7) << 4)))      = h0_; \
    *(bf8*)((char*)(&as_[(buf)][0]) + ra * 128 + ((kc * 2 + 16) ^ ((ra & 7) << 4))) = h1_; \
    } while (0)

#define STG_W(buf, kk) do {                                                       \
    _Pragma("unroll")                                                             \
    for (int i_ = 0; i_ < 4; ++i_) {                                              \
        int c_ = t + i_ * 256; int col_ = c_ >> 3; int gg_ = (c_ & 7) ^ (col_ & 7);\
        gload_lds16(wt + (size_t)(c0 + col_) * D_ + (kk) + gg_ * 8,               \
                    (char*)(&ws_[(buf)][0]) + c_ * 16);                           \
    } } while (0)

    f4 acc[2][4];
    #pragma unroll
    for (int fr = 0; fr < 2; ++fr)
        #pragma unroll
        for (int cf = 0; cf < 4; ++cf) acc[fr][cf] = (f4)0.0f;

    STG_A(0, 0); STG_W(0, 0);
    asm volatile("s_waitcnt vmcnt(0) lgkmcnt(0)" ::: "memory");
    __builtin_amdgcn_s_barrier();
    STG_A(1, 64); STG_W(1, 64);

    #pragma unroll 1
    for (int kt = 0; kt < 9; ++kt) {              // K = 576 = 9*64
        const int cur = kt & 1;
        #pragma unroll
        for (int ks = 0; ks < 2; ++ks) {
            bf8 av[2], bv[4];
            #pragma unroll
            for (int fr = 0; fr < 2; ++fr) {
                int row = wr * 32 + fr * 16 + l15;
                av[fr] = *(const bf8*)((const char*)(&as_[cur][0]) +
                         row * 128 + ((ks * 64 + g * 16) ^ ((row & 7) << 4)));
            }
            #pragma unroll
            for (int cf = 0; cf < 4; ++cf) {
                int col = wc * 64 + cf * 16 + l15;
                bv[cf] = *(const bf8*)((const char*)(&ws_[cur][0]) +
                         col * 128 + ((ks * 64 + g * 16) ^ ((col & 7) << 4)));
            }
            #pragma unroll
            for (int fr = 0; fr < 2; ++fr)
                #pragma unroll
                for (int cf = 0; cf < 4; ++cf)
                    acc[fr][cf] = __builtin_amdgcn_mfma_f32_16x16x32_bf16(av[fr], bv[cf], acc[fr][cf], 0, 0, 0);
        }
        if (kt == 8) break;
        asm volatile("s_waitcnt vmcnt(0) lgkmcnt(0)" ::: "memory");
        __builtin_amdgcn_s_barrier();
        if (kt < 7) { STG_A(cur, (kt + 2) * 64); STG_W(cur, (kt + 2) * 64); }
    }

    #pragma unroll
    for (int fr = 0; fr < 2; ++fr)
        #pragma unroll
        for (int cf = 0; cf < 4; ++cf) {
            int col = c0 + wc * 64 + cf * 16 + l15;
            int row = rows0 + wr * 32 + fr * 16 + g * 4;
            if (isA) {
                float bb = b1[col];
                #pragma unroll
                for (int j = 0; j < 4; ++j)
                    aprojh[(size_t)(row + j) * H1_ + col] = (__bf16)(acc[fr][cf][j] + bb);
            } else {
                #pragma unroll
                for (int j = 0; j < 4; ++j)
                    bprojh[(size_t)(row + j) * H1_ + col] = (__bf16)acc[fr][cf][j];
            }
        }
#undef STG_A
#undef STG_W
}

// -------- k_main: 256thr/4-wave blocks, 2 blocks/CU, 3-slot W2 ring --------
__global__ __launch_bounds__(256, 2) void k_main(
    const __bf16* __restrict__ aprojh, const __bf16* __restrict__ bprojh,
    const __bf16* __restrict__ w2T, const float* __restrict__ b2,
    const float* __restrict__ w3, const float* __restrict__ b3,
    float* __restrict__ outp) {
    __shared__ __bf16 apl[8 * 512];       // 8KB, row=1024B, linear (broadcast)
    __shared__ __bf16 bpl[16 * 512];      // 16KB, row=1024B, XOR swz
    __shared__ __bf16 w2l[3][256 * 32];   // 3x16KB ring
    __shared__ float  part[2][128];       // 1KB -> total 73KB => 2 blocks/CU

    const int t = threadIdx.x, l15 = t & 15, g = (t >> 4) & 3, wid = t >> 6;
    const int wr = wid >> 1, wc = wid & 1;      // 2 x 2 wave grid
    const int bid = blockIdx.x;
    const int bn0 = (bid >> 4) * 8;             // 8 aproj rows (b*N+n)
    const int m0 = (bid & 15) * 16;
    const int bprow0 = ((bn0 >> 10) << 8) + m0; // batch*256 + m0

    // lane-constant LDS read offsets
    int apA[4];
    #pragma unroll
    for (int fr = 0; fr < 4; ++fr) apA[fr] = (wr * 4 + fr) * 1024 + g * 16;
    int offB[8];
    #pragma unroll
    for (int cf = 0; cf < 8; ++cf) {
        int col = wc * 128 + cf * 16 + l15;
        int cp = col >> 1, sp = (((col & 1) << 2) + g) ^ (cp & 7);
        offB[cf] = cp * 128 + sp * 16;
    }
    const int offP = l15 * 1024 + (((g ^ (l15 & 3)) | (l15 & 4)) << 4);

#define STAGE_W2M(stoff, ktn) do {                                                \
    _Pragma("unroll")                                                             \
    for (int i_ = 0; i_ < 4; ++i_) {                                              \
        int c_ = t + i_ * 256; int cp_ = c_ >> 3; int sp_ = c_ & 7;               \
        int si_ = sp_ ^ (cp_ & 7); int col_ = cp_ * 2 + (si_ >> 2);               \
        gload_lds16(w2T + (size_t)col_ * H1_ + (ktn) * 32 + (si_ & 3) * 8,        \
                    (char*)w2l + (stoff) + c_ * 16);                              \
    } } while (0)

#define STAGE_AP() do {                                                           \
    _Pragma("unroll")                                                             \
    for (int i_ = 0; i_ < 2; ++i_) {                                              \
        int c_ = t + i_ * 256;                                                    \
        gload_lds16(aprojh + (size_t)(bn0 + (c_ >> 6)) * H1_ + (c_ & 63) * 8,     \
                    (char*)apl + c_ * 16);                                        \
    } } while (0)

#define STAGE_BP() do {                                                           \
    _Pragma("unroll")                                                             \
    for (int i_ = 0; i_ < 4; ++i_) {                                              \
        int c_ = t + i_ * 256; int row_ = c_ >> 6; int kc_ = (c_ & 63) ^ (row_ & 7);\
        gload_lds16(bprojh + (size_t)(bprow0 + row_) * H1_ + kc_ * 8,             \
                    (char*)bpl + c_ * 16);                                        \
    } } while (0)

    f4 acc[4][8];
    #pragma unroll
    for (int fr = 0; fr < 4; ++fr)
        #pragma unroll
        for (int cf = 0; cf < 8; ++cf) acc[fr][cf] = (f4)0.0f;

    // prologue: ap, bp, w2 slot0 resident; slot1 in flight
    STAGE_AP(); STAGE_BP(); STAGE_W2M(0, 0);     // 10 loads
    STAGE_W2M(16384, 1);                          // +4 = 14
    asm volatile("s_waitcnt vmcnt(4)" ::: "memory");
    __builtin_amdgcn_s_barrier();

    int rdoff = 0, stoff = 32768;
    #pragma unroll 1
    for (int kt = 0; kt < 16; ++kt) {             // K = 512 = 16 * 32
        if (kt < 14) STAGE_W2M(stoff, kt + 2);    // issue early, flies a full phase
        const char* wsl = (const char*)w2l + rdoff;
        bf8 bv[8];
        #pragma unroll
        for (int cf = 0; cf < 8; ++cf) bv[cf] = *(const bf8*)(wsl + offB[cf]);
        bf8 bpv = *(const bf8*)((const char*)bpl + (offP ^ (kt * 64)));
        bf8 apv[4];
        #pragma unroll
        for (int fr = 0; fr < 4; ++fr)
            apv[fr] = *(const bf8*)((const char*)apl + apA[fr] + kt * 64);
        float bpf[8];
        #pragma unroll
        for (int j = 0; j < 8; ++j) bpf[j] = (float)bpv[j];
        __builtin_amdgcn_s_setprio(1);
        #pragma unroll
        for (int fr = 0; fr < 4; ++fr) {
            bf8 av;
            #pragma unroll
            for (int j = 0; j < 4; ++j) {
                av[j]     = (__bf16)fmaxf((float)apv[fr][j]     + bpf[j],     0.0f);
                av[4 + j] = (__bf16)fmaxf((float)apv[fr][4 + j] + bpf[4 + j], 0.0f);
            }
            #pragma unroll
            for (int cf = 0; cf < 8; ++cf)
                acc[fr][cf] = __builtin_amdgcn_mfma_f32_16x16x32_bf16(av, bv[cf], acc[fr][cf], 0, 0, 0);
        }
        __builtin_amdgcn_s_setprio(0);
        if (kt < 14)       asm volatile("s_waitcnt vmcnt(4)" ::: "memory");
        else if (kt == 14) asm volatile("s_waitcnt vmcnt(0)" ::: "memory");
        if (kt < 15) __builtin_amdgcn_s_barrier();
        rdoff = (rdoff == 32768) ? 0 : rdoff + 16384;
        stoff = (stoff == 32768) ? 0 : stoff + 16384;
    }

    // epilogue: relu(acc+b2) dot w3, reduce 16 lanes + 2 wc groups
    float b2v[8], w3v[8];
    #pragma unroll
    for (int cf = 0; cf < 8; ++cf) {
        int col = wc * 128 + cf * 16 + l15;
        b2v[cf] = b2[col]; w3v[cf] = w3[col];
    }
    #pragma unroll
    for (int fr = 0; fr < 4; ++fr) {
        #pragma unroll
        for (int j = 0; j < 4; ++j) {
            float s = 0.0f;
            #pragma unroll
            for (int cf = 0; cf < 8; ++cf)
                s += fmaxf(acc[fr][cf][j] + b2v[cf], 0.0f) * w3v[cf];
            s += __shfl_xor(s, 1); s += __shfl_xor(s, 2);
            s += __shfl_xor(s, 4); s += __shfl_xor(s, 8);
            if (l15 == 0) part[wc][(wr * 4 + fr) * 16 + g * 4 + j] = s;
        }
    }
    __syncthreads();
    if (t < 128) {
        float o = part[0][t] + part[1][t] + b3[0];
        outp[(size_t)(bn0 + (t >> 4)) * M_ + m0 + (t & 15)] = o;
    }
#undef STAGE_W2M
#undef STAGE_AP
#undef STAGE_BP
}

extern "C" void kernel_launch(void* const* d_in, const int* in_sizes, int n_in,
                              void* d_out, int out_size, void* d_ws, size_t ws_size,
                              hipStream_t stream) {
    (void)in_sizes; (void)n_in; (void)out_size; (void)ws_size;
    const float* PhiA = (const float*)d_in[0];
    const float* PhiB = (const float*)d_in[1];
    const float* W1a  = (const float*)d_in[2];
    const float* W1b  = (const float*)d_in[3];
    const float* b1   = (const float*)d_in[4];
    const float* W2   = (const float*)d_in[5];
    const float* b2   = (const float*)d_in[6];
    const float* W3   = (const float*)d_in[7];
    const float* b3   = (const float*)d_in[8];
    float* out = (float*)d_out;

    char* ws = (char*)d_ws;
    __bf16* aprojh = (__bf16*)(ws);                 // 2048*512*2 = 2,097,152
    __bf16* bprojh = (__bf16*)(ws + 2097152);       //  512*512*2 =   524,288
    __bf16* w1aT   = (__bf16*)(ws + 2621440);       //   589,824
    __bf16* w1bT   = (__bf16*)(ws + 3211264);       //   589,824
    __bf16* w2T    = (__bf16*)(ws + 3801088);       //   262,144  (total ~4.1 MB)

    k_prep<<<176, 256, 0, stream>>>(W1a, W1b, W2, w1aT, w1bT, w2T);
    k_proj<<<dim3(40, 4), 256, 0, stream>>>(PhiA, PhiB, w1aT, w1bT, b1, aprojh, bprojh);
    k_main<<<4096, 256, 0, stream>>>(aprojh, bprojh, w2T, b2, W3, b3, out);
}

// Round 10
// 229.681 us; speedup vs baseline: 1.0907x; 1.0898x over previous
//
#include <hip/hip_runtime.h>

typedef float    f4 __attribute__((ext_vector_type(4)));
typedef _Float16 h8 __attribute__((ext_vector_type(8)));

constexpr int B_ = 2, N_ = 1024, M_ = 256, D_ = 576, H1_ = 512, H2_ = 256;

__device__ __forceinline__ void gload_lds16(const void* g, void* l) {
    __builtin_amdgcn_global_load_lds((const __attribute__((address_space(1))) void*)g,
                                     (__attribute__((address_space(3))) void*)l, 16, 0, 0);
}

// ---------------- k_prep: 64x64 f32->f16 transposes (W1a,W1b,W2) -----------
__global__ __launch_bounds__(256) void k_prep(
    const float* __restrict__ W1a, const float* __restrict__ W1b, const float* __restrict__ W2,
    _Float16* __restrict__ w1aT, _Float16* __restrict__ w1bT, _Float16* __restrict__ w2T) {
    __shared__ float tl[64][65];
    int bid = blockIdx.x;
    const float* src; _Float16* dst; int R, C, t0;
    if (bid < 72)       { src = W1a; dst = w1aT; R = D_;  C = H1_; t0 = bid; }
    else if (bid < 144) { src = W1b; dst = w1bT; R = D_;  C = H1_; t0 = bid - 72; }
    else                { src = W2;  dst = w2T;  R = H1_; C = H2_; t0 = bid - 144; }
    const int tilesC = C / 64;
    const int r0 = (t0 / tilesC) * 64, c0 = (t0 % tilesC) * 64;
    const int tx = threadIdx.x & 63, ty = threadIdx.x >> 6;
    #pragma unroll
    for (int i = 0; i < 16; ++i)
        tl[ty + i * 4][tx] = src[(size_t)(r0 + ty + i * 4) * C + c0 + tx];
    __syncthreads();
    #pragma unroll
    for (int i = 0; i < 16; ++i)
        dst[(size_t)(c0 + ty + i * 4) * R + r0 + tx] = (_Float16)tl[tx][ty + i * 4];
}

// ------- k_proj: Phi(f32) @ W1T -> aprojh(f16,+b1) / bprojh(f16) -----------
// 64r x 128c tile, 4 waves (2x2), BK=64, double-buffered.
__global__ __launch_bounds__(256, 2) void k_proj(
    const float* __restrict__ PhiA, const float* __restrict__ PhiB,
    const _Float16* __restrict__ w1aT, const _Float16* __restrict__ w1bT,
    const float* __restrict__ b1, _Float16* __restrict__ aprojh, _Float16* __restrict__ bprojh) {
    __shared__ _Float16 as_[2][64 * 64];    // 8KB each, row=128B, XOR swz
    __shared__ _Float16 ws_[2][128 * 64];   // 16KB each
    const int t = threadIdx.x, l15 = t & 15, g = (t >> 4) & 3, wid = t >> 6;
    const int wr = wid >> 1, wc = wid & 1;        // 2 x 2 waves
    const int by = blockIdx.x, c0 = blockIdx.y * 128;
    const bool isA = (by < 32);
    const float* srcf = isA ? PhiA : PhiB;
    const int rows0 = isA ? by * 64 : (by - 32) * 64;
    const _Float16* wt = isA ? w1aT : w1bT;

    const int ra = t >> 2, kc = (t & 3) * 16;     // A reg-stage: row, 16-k chunk

#define STG_A(buf, kk) do {                                                       \
    const float* ap_ = srcf + (size_t)(rows0 + ra) * D_ + (kk) + kc;              \
    f4 v0_ = *(const f4*)ap_, v1_ = *(const f4*)(ap_ + 4),                        \
       v2_ = *(const f4*)(ap_ + 8), v3_ = *(const f4*)(ap_ + 12);                 \
    h8 h0_, h1_;                                                                  \
    _Pragma("unroll")                                                             \
    for (int j_ = 0; j_ < 4; ++j_) {                                              \
        h0_[j_] = (_Float16)v0_[j_]; h0_[4 + j_] = (_Float16)v1_[j_];             \
        h1_[j_] = (_Float16)v2_[j_]; h1_[4 + j_] = (_Float16)v3_[j_];             \
    }                                                                             \
    *(h8*)((char*)(&as_[(buf)][0]) + ra * 128 + ((kc * 2) ^ ((ra & 7) << 4)))      = h0_; \
    *(h8*)((char*)(&as_[(buf)][0]) + ra * 128 + ((kc * 2 + 16) ^ ((ra & 7) << 4))) = h1_; \
    } while (0)

#define STG_W(buf, kk) do {                                                       \
    _Pragma("unroll")                                                             \
    for (int i_ = 0; i_ < 4; ++i_) {                                              \
        int c_ = t + i_ * 256; int col_ = c_ >> 3; int gg_ = (c_ & 7) ^ (col_ & 7);\
        gload_lds16(wt + (size_t)(c0 + col_) * D_ + (kk) + gg_ * 8,               \
                    (char*)(&ws_[(buf)][0]) + c_ * 16);                           \
    } } while (0)

    f4 acc[2][4];
    #pragma unroll
    for (int fr = 0; fr < 2; ++fr)
        #pragma unroll
        for (int cf = 0; cf < 4; ++cf) acc[fr][cf] = (f4)0.0f;

    STG_A(0, 0); STG_W(0, 0);
    asm volatile("s_waitcnt vmcnt(0) lgkmcnt(0)" ::: "memory");
    __builtin_amdgcn_s_barrier();
    STG_A(1, 64); STG_W(1, 64);

    #pragma unroll 1
    for (int kt = 0; kt < 9; ++kt) {              // K = 576 = 9*64
        const int cur = kt & 1;
        #pragma unroll
        for (int ks = 0; ks < 2; ++ks) {
            h8 av[2], bv[4];
            #pragma unroll
            for (int fr = 0; fr < 2; ++fr) {
                int row = wr * 32 + fr * 16 + l15;
                av[fr] = *(const h8*)((const char*)(&as_[cur][0]) +
                         row * 128 + ((ks * 64 + g * 16) ^ ((row & 7) << 4)));
            }
            #pragma unroll
            for (int cf = 0; cf < 4; ++cf) {
                int col = wc * 64 + cf * 16 + l15;
                bv[cf] = *(const h8*)((const char*)(&ws_[cur][0]) +
                         col * 128 + ((ks * 64 + g * 16) ^ ((col & 7) << 4)));
            }
            #pragma unroll
            for (int fr = 0; fr < 2; ++fr)
                #pragma unroll
                for (int cf = 0; cf < 4; ++cf)
                    acc[fr][cf] = __builtin_amdgcn_mfma_f32_16x16x32_f16(av[fr], bv[cf], acc[fr][cf], 0, 0, 0);
        }
        if (kt == 8) break;
        asm volatile("s_waitcnt vmcnt(0) lgkmcnt(0)" ::: "memory");
        __builtin_amdgcn_s_barrier();
        if (kt < 7) { STG_A(cur, (kt + 2) * 64); STG_W(cur, (kt + 2) * 64); }
    }

    #pragma unroll
    for (int fr = 0; fr < 2; ++fr)
        #pragma unroll
        for (int cf = 0; cf < 4; ++cf) {
            int col = c0 + wc * 64 + cf * 16 + l15;
            int row = rows0 + wr * 32 + fr * 16 + g * 4;
            if (isA) {
                float bb = b1[col];
                #pragma unroll
                for (int j = 0; j < 4; ++j)
                    aprojh[(size_t)(row + j) * H1_ + col] = (_Float16)(acc[fr][cf][j] + bb);
            } else {
                #pragma unroll
                for (int j = 0; j < 4; ++j)
                    bprojh[(size_t)(row + j) * H1_ + col] = (_Float16)acc[fr][cf][j];
            }
        }
#undef STG_A
#undef STG_W
}

// -------- k_main: f16 packed build, 4 waves, 2 blocks/CU, 3-slot ring ------
__global__ __launch_bounds__(256, 2) void k_main(
    const _Float16* __restrict__ aprojh, const _Float16* __restrict__ bprojh,
    const _Float16* __restrict__ w2T, const float* __restrict__ b2,
    const float* __restrict__ w3, const float* __restrict__ b3,
    float* __restrict__ outp) {
    __shared__ _Float16 apl[8 * 512];       // 8KB, row=1024B, linear (broadcast)
    __shared__ _Float16 bpl[16 * 512];      // 16KB, row=1024B, XOR swz
    __shared__ _Float16 w2l[3][256 * 32];   // 3x16KB ring
    __shared__ float    part[2][128];       // 1KB -> total 73KB => 2 blocks/CU

    const int t = threadIdx.x, l15 = t & 15, g = (t >> 4) & 3, wid = t >> 6;
    const int wr = wid >> 1, wc = wid & 1;      // 2 x 2 wave grid
    const int bid = blockIdx.x;
    const int bn0 = (bid >> 4) * 8;             // 8 aproj rows (b*N+n)
    const int m0 = (bid & 15) * 16;
    const int bprow0 = ((bn0 >> 10) << 8) + m0; // batch*256 + m0

    // lane-constant LDS read offsets
    int apA[4];
    #pragma unroll
    for (int fr = 0; fr < 4; ++fr) apA[fr] = (wr * 4 + fr) * 1024 + g * 16;
    int offB[8];
    #pragma unroll
    for (int cf = 0; cf < 8; ++cf) {
        int col = wc * 128 + cf * 16 + l15;
        int cp = col >> 1, sp = (((col & 1) << 2) + g) ^ (cp & 7);
        offB[cf] = cp * 128 + sp * 16;
    }
    const int offP = l15 * 1024 + (((g ^ (l15 & 3)) | (l15 & 4)) << 4);

#define STAGE_W2M(stoff, ktn) do {                                                \
    _Pragma("unroll")                                                             \
    for (int i_ = 0; i_ < 4; ++i_) {                                              \
        int c_ = t + i_ * 256; int cp_ = c_ >> 3; int sp_ = c_ & 7;               \
        int si_ = sp_ ^ (cp_ & 7); int col_ = cp_ * 2 + (si_ >> 2);               \
        gload_lds16(w2T + (size_t)col_ * H1_ + (ktn) * 32 + (si_ & 3) * 8,        \
                    (char*)w2l + (stoff) + c_ * 16);                              \
    } } while (0)

#define STAGE_AP() do {                                                           \
    _Pragma("unroll")                                                             \
    for (int i_ = 0; i_ < 2; ++i_) {                                              \
        int c_ = t + i_ * 256;                                                    \
        gload_lds16(aprojh + (size_t)(bn0 + (c_ >> 6)) * H1_ + (c_ & 63) * 8,     \
                    (char*)apl + c_ * 16);                                        \
    } } while (0)

#define STAGE_BP() do {                                                           \
    _Pragma("unroll")                                                             \
    for (int i_ = 0; i_ < 4; ++i_) {                                              \
        int c_ = t + i_ * 256; int row_ = c_ >> 6; int kc_ = (c_ & 63) ^ (row_ & 7);\
        gload_lds16(bprojh + (size_t)(bprow0 + row_) * H1_ + kc_ * 8,             \
                    (char*)bpl + c_ * 16);                                        \
    } } while (0)

    f4 acc[4][8];
    #pragma unroll
    for (int fr = 0; fr < 4; ++fr)
        #pragma unroll
        for (int cf = 0; cf < 8; ++cf) acc[fr][cf] = (f4)0.0f;

    // prologue: ap, bp, w2 slot0 resident; slot1 in flight
    STAGE_AP(); STAGE_BP(); STAGE_W2M(0, 0);     // 10 loads
    STAGE_W2M(16384, 1);                          // +4 = 14
    asm volatile("s_waitcnt vmcnt(4)" ::: "memory");
    __builtin_amdgcn_s_barrier();

    const h8 h8z = (h8)(_Float16)0;
    int rdoff = 0, stoff = 32768;
    #pragma unroll 1
    for (int kt = 0; kt < 16; ++kt) {             // K = 512 = 16 * 32
        if (kt < 14) STAGE_W2M(stoff, kt + 2);    // issue early, flies a full phase
        const char* wsl = (const char*)w2l + rdoff;
        h8 bv[8];
        #pragma unroll
        for (int cf = 0; cf < 8; ++cf) bv[cf] = *(const h8*)(wsl + offB[cf]);
        h8 bpv = *(const h8*)((const char*)bpl + (offP ^ (kt * 64)));
        h8 apv[4];
        #pragma unroll
        for (int fr = 0; fr < 4; ++fr)
            apv[fr] = *(const h8*)((const char*)apl + apA[fr] + kt * 64);
        __builtin_amdgcn_s_setprio(1);
        #pragma unroll
        for (int fr = 0; fr < 4; ++fr) {
            h8 av = __builtin_elementwise_max(apv[fr] + bpv, h8z);  // v_pk_add_f16 + v_pk_max_f16
            #pragma unroll
            for (int cf = 0; cf < 8; ++cf)
                acc[fr][cf] = __builtin_amdgcn_mfma_f32_16x16x32_f16(av, bv[cf], acc[fr][cf], 0, 0, 0);
        }
        __builtin_amdgcn_s_setprio(0);
        if (kt < 14)       asm volatile("s_waitcnt vmcnt(4)" ::: "memory");
        else if (kt == 14) asm volatile("s_waitcnt vmcnt(0)" ::: "memory");
        if (kt < 15) __builtin_amdgcn_s_barrier();
        rdoff = (rdoff == 32768) ? 0 : rdoff + 16384;
        stoff = (stoff == 32768) ? 0 : stoff + 16384;
    }

    // epilogue: relu(acc+b2) dot w3, reduce 16 lanes + 2 wc groups
    float b2v[8], w3v[8];
    #pragma unroll
    for (int cf = 0; cf < 8; ++cf) {
        int col = wc * 128 + cf * 16 + l15;
        b2v[cf] = b2[col]; w3v[cf] = w3[col];
    }
    #pragma unroll
    for (int fr = 0; fr < 4; ++fr) {
        #pragma unroll
        for (int j = 0; j < 4; ++j) {
            float s = 0.0f;
            #pragma unroll
            for (int cf = 0; cf < 8; ++cf)
                s += fmaxf(acc[fr][cf][j] + b2v[cf], 0.0f) * w3v[cf];
            s += __shfl_xor(s, 1); s += __shfl_xor(s, 2);
            s += __shfl_xor(s, 4); s += __shfl_xor(s, 8);
            if (l15 == 0) part[wc][(wr * 4 + fr) * 16 + g * 4 + j] = s;
        }
    }
    __syncthreads();
    if (t < 128) {
        float o = part[0][t] + part[1][t] + b3[0];
        outp[(size_t)(bn0 + (t >> 4)) * M_ + m0 + (t & 15)] = o;
    }
#undef STAGE_W2M
#undef STAGE_AP
#undef STAGE_BP
}

extern "C" void kernel_launch(void* const* d_in, const int* in_sizes, int n_in,
                              void* d_out, int out_size, void* d_ws, size_t ws_size,
                              hipStream_t stream) {
    (void)in_sizes; (void)n_in; (void)out_size; (void)ws_size;
    const float* PhiA = (const float*)d_in[0];
    const float* PhiB = (const float*)d_in[1];
    const float* W1a  = (const float*)d_in[2];
    const float* W1b  = (const float*)d_in[3];
    const float* b1   = (const float*)d_in[4];
    const float* W2   = (const float*)d_in[5];
    const float* b2   = (const float*)d_in[6];
    const float* W3   = (const float*)d_in[7];
    const float* b3   = (const float*)d_in[8];
    float* out = (float*)d_out;

    char* ws = (char*)d_ws;
    _Float16* aprojh = (_Float16*)(ws);                 // 2048*512*2 = 2,097,152
    _Float16* bprojh = (_Float16*)(ws + 2097152);       //  512*512*2 =   524,288
    _Float16* w1aT   = (_Float16*)(ws + 2621440);       //   589,824
    _Float16* w1bT   = (_Float16*)(ws + 3211264);       //   589,824
    _Float16* w2T    = (_Float16*)(ws + 3801088);       //   262,144  (total ~4.1 MB)

    k_prep<<<176, 256, 0, stream>>>(W1a, W1b, W2, w1aT, w1bT, w2T);
    k_proj<<<dim3(40, 4), 256, 0, stream>>>(PhiA, PhiB, w1aT, w1bT, b1, aprojh, bprojh);
    k_main<<<4096, 256, 0, stream>>>(aprojh, bprojh, w2T, b2, W3, b3, out);
}